// Round 1
// baseline (270.776 us; speedup 1.0000x reference)
//
#include <hip/hip_runtime.h>

#define Z_TOTAL 32768
#define ZC 16                 // z-chunk per block
#define NPAIR 1024            // 32*32 (b,c) or (c,d) pairs
#define THREADS 256

// y1[a,c,z] = sum_b x1[a,b,z] * x0[b,c,z]
// y2[a,d,z] = sum_c y1[a,c,z] * x2[c,d,z]
__global__ __launch_bounds__(THREADS, 2) void einnet_kernel(
    const float* __restrict__ x0,   // (b,c,Z)
    const float* __restrict__ x1,   // (a,b,Z)
    const float* __restrict__ x2,   // (c,d,Z)
    float* __restrict__ out)        // (a,d,Z)
{
    __shared__ float lds[NPAIR * ZC];   // 64 KiB, reused for x0 then x2

    const int tid = threadIdx.x;
    const int z0  = blockIdx.x * ZC;
    const int zl  = tid & (ZC - 1);     // 0..15  (fastest in tid -> coalescing)
    const int ag  = tid >> 4;           // 0..15  row-pair group
    const int a0  = ag * 2;
    const int z   = z0 + zl;

    // ---- stage x0 tile: lds[pair*ZC + zz] = x0[pair*Z + z0 + zz]
    // 4096 float4 loads, 16 per thread, fully coalesced in 64B segments
    #pragma unroll
    for (int i = 0; i < 16; ++i) {
        int idx = tid + i * THREADS;          // 0..4095
        int p = idx >> 2;                     // pair 0..1023
        int q = idx & 3;                      // float4 slot within z-chunk
        float4 v = *reinterpret_cast<const float4*>(
            x0 + (size_t)p * Z_TOTAL + z0 + q * 4);
        *reinterpret_cast<float4*>(&lds[idx * 4]) = v;
    }

    __syncthreads();

    // ---- prefetch x2 tile into registers; consumed after phase 1 so the
    // HBM latency hides under phase-1 compute (async-stage split).
    float4 xr[16];
    #pragma unroll
    for (int i = 0; i < 16; ++i) {
        int idx = tid + i * THREADS;
        int p = idx >> 2;
        int q = idx & 3;
        xr[i] = *reinterpret_cast<const float4*>(
            x2 + (size_t)p * Z_TOTAL + z0 + q * 4);
    }

    // ---- phase 1: two y1 rows (a0, a0+1) in registers
    float y1a[32], y1b[32];
    #pragma unroll
    for (int c = 0; c < 32; ++c) { y1a[c] = 0.f; y1b[c] = 0.f; }

    const float* pa = x1 + (size_t)(a0 * 32) * Z_TOTAL + z;
    const float* pb = pa + (size_t)32 * Z_TOTAL;

    float va = pa[0];
    float vb = pb[0];
    #pragma unroll 1
    for (int b = 0; b < 32; ++b) {
        int bn = (b + 1) & 31;                 // harmless wrap on last iter
        float van = pa[bn * Z_TOTAL];
        float vbn = pb[bn * Z_TOTAL];
        const float* lp = &lds[(b * 32) * ZC + zl];
        #pragma unroll
        for (int c = 0; c < 32; ++c) {
            float s = lp[c * ZC];              // broadcast across ag, no conflict
            y1a[c] = fmaf(va, s, y1a[c]);
            y1b[c] = fmaf(vb, s, y1b[c]);
        }
        va = van; vb = vbn;
    }

    __syncthreads();   // all reads of x0 tile done

    // ---- write prefetched x2 tile into LDS
    #pragma unroll
    for (int i = 0; i < 16; ++i) {
        *reinterpret_cast<float4*>(&lds[(tid + i * THREADS) * 4]) = xr[i];
    }

    __syncthreads();

    // ---- phase 2: y2 rows
    float y2a[32], y2b[32];
    #pragma unroll
    for (int d = 0; d < 32; ++d) { y2a[d] = 0.f; y2b[d] = 0.f; }

    #pragma unroll 1
    for (int c = 0; c < 32; ++c) {
        const float* lp = &lds[(c * 32) * ZC + zl];
        float wa = y1a[c];
        float wb = y1b[c];
        #pragma unroll
        for (int d = 0; d < 32; ++d) {
            float s = lp[d * ZC];
            y2a[d] = fmaf(wa, s, y2a[d]);
            y2b[d] = fmaf(wb, s, y2b[d]);
        }
    }

    // ---- store y2 rows
    float* oa = out + (size_t)(a0 * 32) * Z_TOTAL + z;
    float* ob = oa + (size_t)32 * Z_TOTAL;
    #pragma unroll
    for (int d = 0; d < 32; ++d) {
        oa[d * Z_TOTAL] = y2a[d];
        ob[d * Z_TOTAL] = y2b[d];
    }
}

extern "C" void kernel_launch(void* const* d_in, const int* in_sizes, int n_in,
                              void* d_out, int out_size, void* d_ws, size_t ws_size,
                              hipStream_t stream) {
    const float* x0 = (const float*)d_in[0];  // (b,c,Z)
    const float* x1 = (const float*)d_in[1];  // (a,b,Z)
    const float* x2 = (const float*)d_in[2];  // (c,d,Z)
    float* out = (float*)d_out;

    dim3 grid(Z_TOTAL / ZC);   // 2048 blocks
    dim3 block(THREADS);
    hipLaunchKernelGGL(einnet_kernel, grid, block, 0, stream, x0, x1, x2, out);
}

// Round 2
// 178.998 us; speedup vs baseline: 1.5127x; 1.5127x over previous
//
#include <hip/hip_runtime.h>

#define Z_TOTAL 32768
#define ZC 32
#define THREADS 256

// y1[a,c,z] = sum_b x1[a,b,z] * x0[b,c,z]
// y2[a,d,z] = sum_c y1[a,c,z] * x2[c,d,z]
//
// Block = 32 z-lanes x 8 a-groups (Ar=2) covering 16 a-rows (one a-half).
// Two blocks per z-chunk (a-halves), XCD-pair-swizzled so they share L2 tiles.
// x0/x2 staged in 32 KiB quarter tiles, layout [pair4][z32][4] so compute
// reads are stride-1 ds_read_b128 (broadcast across a-groups).
__global__ __launch_bounds__(THREADS, 3) void einnet_kernel(
    const float* __restrict__ x0,   // (b,c,Z)
    const float* __restrict__ x1,   // (a,b,Z)
    const float* __restrict__ x2,   // (c,d,Z)
    float* __restrict__ out)        // (a,d,Z)
{
    __shared__ float lds[8192];   // 32 KiB quarter tile

    const int tid = threadIdx.x;
    const int bid = blockIdx.x;
    // pair the two a-half blocks of one z-chunk onto the same XCD
    const int zc    = (bid >> 4) * 8 + (bid & 7);   // 0..1023
    const int ahalf = (bid >> 3) & 1;
    const int z0 = zc * ZC;
    const int zl = tid & 31;           // z lane
    const int ag = tid >> 5;           // 0..7 a-group
    const int a0 = ahalf * 16 + ag * 2;

    float y1[2][32];
    float y2[2][32];
    #pragma unroll
    for (int r = 0; r < 2; ++r) {
        #pragma unroll
        for (int c = 0; c < 32; ++c) { y1[r][c] = 0.f; y2[r][c] = 0.f; }
    }

    // ---------------- phase 1: y1 = x1 . x0, b in quarters of 8 ----------------
    #pragma unroll 1
    for (int bq = 0; bq < 4; ++bq) {
        // x1 quarter into registers: issue FIRST so HBM latency hides under staging
        float x1q[2][8];
        #pragma unroll
        for (int r = 0; r < 2; ++r) {
            #pragma unroll
            for (int bl = 0; bl < 8; ++bl)
                x1q[r][bl] = x1[(size_t)((a0 + r) * 32 + bq * 8 + bl) * Z_TOTAL + z0 + zl];
        }

        __syncthreads();   // previous quarter's LDS reads complete
        // stage x0[bq*8..+8, all c, z0..z0+31]; gather 4 c per thread, write b128
        #pragma unroll
        for (int i = 0; i < 8; ++i) {
            int w   = tid + i * THREADS;   // float4 slot 0..2047
            int pc4 = w >> 5;              // bl*8 + c4
            int zs  = w & 31;
            const float* g = x0 + (size_t)(bq * 256 + pc4 * 4) * Z_TOTAL + z0 + zs;
            float4 v;
            v.x = g[0];
            v.y = g[(size_t)Z_TOTAL];
            v.z = g[2 * (size_t)Z_TOTAL];
            v.w = g[3 * (size_t)Z_TOTAL];
            *reinterpret_cast<float4*>(&lds[w * 4]) = v;
        }
        __syncthreads();

        #pragma unroll
        for (int bl = 0; bl < 8; ++bl) {
            #pragma unroll
            for (int c4 = 0; c4 < 8; ++c4) {
                float4 s = *reinterpret_cast<const float4*>(&lds[((bl * 8 + c4) * 32 + zl) * 4]);
                #pragma unroll
                for (int r = 0; r < 2; ++r) {
                    y1[r][c4 * 4 + 0] = fmaf(x1q[r][bl], s.x, y1[r][c4 * 4 + 0]);
                    y1[r][c4 * 4 + 1] = fmaf(x1q[r][bl], s.y, y1[r][c4 * 4 + 1]);
                    y1[r][c4 * 4 + 2] = fmaf(x1q[r][bl], s.z, y1[r][c4 * 4 + 2]);
                    y1[r][c4 * 4 + 3] = fmaf(x1q[r][bl], s.w, y1[r][c4 * 4 + 3]);
                }
            }
        }
    }

    // ---------------- phase 2: y2 = y1 . x2, c in quarters of 8 ----------------
    #pragma unroll
    for (int cq = 0; cq < 4; ++cq) {     // full unroll: y1[cq*8+cl8] must be static
        __syncthreads();
        #pragma unroll
        for (int i = 0; i < 8; ++i) {
            int w   = tid + i * THREADS;
            int pc4 = w >> 5;              // cl8*8 + d4
            int zs  = w & 31;
            const float* g = x2 + (size_t)(cq * 256 + pc4 * 4) * Z_TOTAL + z0 + zs;
            float4 v;
            v.x = g[0];
            v.y = g[(size_t)Z_TOTAL];
            v.z = g[2 * (size_t)Z_TOTAL];
            v.w = g[3 * (size_t)Z_TOTAL];
            *reinterpret_cast<float4*>(&lds[w * 4]) = v;
        }
        __syncthreads();

        #pragma unroll
        for (int cl8 = 0; cl8 < 8; ++cl8) {
            #pragma unroll
            for (int d4 = 0; d4 < 8; ++d4) {
                float4 s = *reinterpret_cast<const float4*>(&lds[((cl8 * 8 + d4) * 32 + zl) * 4]);
                #pragma unroll
                for (int r = 0; r < 2; ++r) {
                    float w1 = y1[r][cq * 8 + cl8];
                    y2[r][d4 * 4 + 0] = fmaf(w1, s.x, y2[r][d4 * 4 + 0]);
                    y2[r][d4 * 4 + 1] = fmaf(w1, s.y, y2[r][d4 * 4 + 1]);
                    y2[r][d4 * 4 + 2] = fmaf(w1, s.z, y2[r][d4 * 4 + 2]);
                    y2[r][d4 * 4 + 3] = fmaf(w1, s.w, y2[r][d4 * 4 + 3]);
                }
            }
        }
    }

    // ---------------- store: 128 B segments per (a,d) row ----------------
    #pragma unroll
    for (int r = 0; r < 2; ++r) {
        #pragma unroll
        for (int d = 0; d < 32; ++d)
            out[(size_t)((a0 + r) * 32 + d) * Z_TOTAL + z0 + zl] = y2[r][d];
    }
}

extern "C" void kernel_launch(void* const* d_in, const int* in_sizes, int n_in,
                              void* d_out, int out_size, void* d_ws, size_t ws_size,
                              hipStream_t stream) {
    const float* x0 = (const float*)d_in[0];  // (b,c,Z)
    const float* x1 = (const float*)d_in[1];  // (a,b,Z)
    const float* x2 = (const float*)d_in[2];  // (c,d,Z)
    float* out = (float*)d_out;

    dim3 grid(2048);   // 1024 z-chunks x 2 a-halves
    dim3 block(THREADS);
    hipLaunchKernelGGL(einnet_kernel, grid, block, 0, stream, x0, x1, x2, out);
}